// Round 5
// baseline (134.622 us; speedup 1.0000x reference)
//
#include <hip/hip_runtime.h>
#include <math.h>

#define SEQ   2048
#define VOCAB 50000
#define EMBD  50
#define L1OUT 2054      // (2048+12) - 7 + 1
#define NTOK  2060      // padded-token index space i = 0..2059 (g = i-6)
#define DSTR  2064      // LDS row stride for Dv (SoA)

// ---- fallback prep (only if ws too small for D): Wm + zero acc/cnt --------
__global__ void __launch_bounds__(384)
prep_kernel(const float* __restrict__ W1, float* __restrict__ ws) {
    int t = threadIdx.x;
    if (t < 350) {
        float s = 0.f;
        #pragma unroll
        for (int c = 0; c < 6; ++c) s += W1[t * 6 + c];
        ws[t] = s * (1.0f / 6.0f);
    } else if (t < 358) {
        ws[t] = 0.f;                        // acc/cnt/acc2/cnt2/dummy region
    }
}

// ---- build_d (fused Wm): D[v][0..6] = dot(emb[v], Wm[kw]); zero acc/cnt ---
__global__ void __launch_bounds__(256)
build_d(const float* __restrict__ emb, const float* __restrict__ W1,
        float* __restrict__ D, float* __restrict__ accs) {
    __shared__ float wm[352];
    int t = threadIdx.x;
    for (int i = t; i < 350; i += 256) {
        float s = 0.f;
        #pragma unroll
        for (int c = 0; c < 6; ++c) s += W1[i * 6 + c];
        wm[i] = s * (1.0f / 6.0f);
    }
    if (blockIdx.x == 0 && t < 5) accs[t] = 0.f;   // acc,cnt,acc2,cnt2,dummy
    __syncthreads();

    int v = blockIdx.x * 256 + t;
    if (v >= VOCAB) return;
    const float2* row = (const float2*)(emb + (size_t)v * EMBD);
    float d[7] = {0.f, 0.f, 0.f, 0.f, 0.f, 0.f, 0.f};
    for (int e = 0; e < 25; ++e) {
        float2 r = row[e];
        #pragma unroll
        for (int kw = 0; kw < 7; ++kw)
            d[kw] = fmaf(r.y, wm[kw * 50 + 2 * e + 1],
                    fmaf(r.x, wm[kw * 50 + 2 * e], d[kw]));
    }
    float4* out = (float4*)(D + (size_t)v * 8);
    out[0] = make_float4(d[0], d[1], d[2], d[3]);
    out[1] = make_float4(d[4], d[5], d[6], 0.f);
}

// ---- main: one block (512 thr) per batch; fused finalize via atomics ------
template<int USE_D>
__global__ void __launch_bounds__(512, 1)
dcnn_main(const int* __restrict__ x, const float* __restrict__ emb,
          const float* __restrict__ W1, const float* __restrict__ b1,
          const float* __restrict__ W2, const float* __restrict__ b2,
          const float* __restrict__ Wd, const float* __restrict__ bd,
          const float* __restrict__ Dtab, const float* __restrict__ wm,
          float* __restrict__ acc, int* __restrict__ cnt,
          float* __restrict__ out)
{
    __shared__ float Dv[7][DSTR];         // 57.8 KB SoA per-token dot values
    __shared__ float cand_v[64];
    __shared__ int   cand_i[64];
    __shared__ int   topi[8];
    __shared__ float part[240];
    __shared__ float s1p[16][6];
    __shared__ float out2[12][14];
    __shared__ float exc2[12];

    const int b   = blockIdx.x;
    const int tid = threadIdx.x;
    const int* xb = x + b * SEQ;

    // ---- fully-unrolled 2-phase gather: all xb loads, then all D loads ----
    // slots k=0..4: padded index i = tid + 512k, token g = i - 6
    {
        int tk0 = (tid >= 6) ? xb[tid - 6]   : -1;
        int tk1 = xb[tid + 506];
        int tk2 = xb[tid + 1018];
        int tk3 = xb[tid + 1530];
        int tk4 = (tid < 6)  ? xb[tid + 2042] : -1;

        float4 lo0 = {0,0,0,0}, hi0 = {0,0,0,0};
        float4 lo1 = {0,0,0,0}, hi1 = {0,0,0,0};
        float4 lo2 = {0,0,0,0}, hi2 = {0,0,0,0};
        float4 lo3 = {0,0,0,0}, hi3 = {0,0,0,0};
        float4 lo4 = {0,0,0,0}, hi4 = {0,0,0,0};
        if (USE_D) {
            const float4* dp;
            if (tk0 >= 0) { dp = (const float4*)(Dtab + (size_t)tk0 * 8); lo0 = dp[0]; hi0 = dp[1]; }
            { dp = (const float4*)(Dtab + (size_t)tk1 * 8); lo1 = dp[0]; hi1 = dp[1]; }
            { dp = (const float4*)(Dtab + (size_t)tk2 * 8); lo2 = dp[0]; hi2 = dp[1]; }
            { dp = (const float4*)(Dtab + (size_t)tk3 * 8); lo3 = dp[0]; hi3 = dp[1]; }
            if (tk4 >= 0) { dp = (const float4*)(Dtab + (size_t)tk4 * 8); lo4 = dp[0]; hi4 = dp[1]; }
        } else {
            #pragma unroll
            for (int k = 0; k < 5; ++k) {
                int tk = (k==0)?tk0:(k==1)?tk1:(k==2)?tk2:(k==3)?tk3:tk4;
                if (tk < 0) continue;
                const float2* row = (const float2*)(emb + (size_t)tk * EMBD);
                float dd[7] = {0,0,0,0,0,0,0};
                for (int e = 0; e < 25; ++e) {
                    float2 r = row[e];
                    #pragma unroll
                    for (int kw = 0; kw < 7; ++kw)
                        dd[kw] = fmaf(r.y, wm[kw * 50 + 2 * e + 1],
                                 fmaf(r.x, wm[kw * 50 + 2 * e], dd[kw]));
                }
                float4 l = {dd[0],dd[1],dd[2],dd[3]}, h = {dd[4],dd[5],dd[6],0.f};
                if (k==0){lo0=l;hi0=h;} else if(k==1){lo1=l;hi1=h;}
                else if(k==2){lo2=l;hi2=h;} else if(k==3){lo3=l;hi3=h;}
                else {lo4=l;hi4=h;}
            }
        }
        int i0 = tid, i1 = tid + 512, i2 = tid + 1024, i3 = tid + 1536;
        Dv[0][i0]=lo0.x; Dv[1][i0]=lo0.y; Dv[2][i0]=lo0.z; Dv[3][i0]=lo0.w;
        Dv[4][i0]=hi0.x; Dv[5][i0]=hi0.y; Dv[6][i0]=hi0.z;
        Dv[0][i1]=lo1.x; Dv[1][i1]=lo1.y; Dv[2][i1]=lo1.z; Dv[3][i1]=lo1.w;
        Dv[4][i1]=hi1.x; Dv[5][i1]=hi1.y; Dv[6][i1]=hi1.z;
        Dv[0][i2]=lo2.x; Dv[1][i2]=lo2.y; Dv[2][i2]=lo2.z; Dv[3][i2]=lo2.w;
        Dv[4][i2]=hi2.x; Dv[5][i2]=hi2.y; Dv[6][i2]=hi2.z;
        Dv[0][i3]=lo3.x; Dv[1][i3]=lo3.y; Dv[2][i3]=lo3.z; Dv[3][i3]=lo3.w;
        Dv[4][i3]=hi3.x; Dv[5][i3]=hi3.y; Dv[6][i3]=hi3.z;
        if (tid < 12) {
            int i4 = tid + 2048;
            Dv[0][i4]=lo4.x; Dv[1][i4]=lo4.y; Dv[2][i4]=lo4.z; Dv[3][i4]=lo4.w;
            Dv[4][i4]=hi4.x; Dv[5][i4]=hi4.y; Dv[6][i4]=hi4.z;
        }
    }
    __syncthreads();

    // ---- excitements in registers: slots k=0..4, position t = tid + 512k ----
    float ev[5];
    #pragma unroll
    for (int k = 0; k < 4; ++k) {
        int t = tid + 512 * k;
        ev[k] = ((Dv[0][t] + Dv[1][t + 1]) + (Dv[2][t + 2] + Dv[3][t + 3]))
              + ((Dv[4][t + 4] + Dv[5][t + 5]) + Dv[6][t + 6]);
    }
    if (tid < 6) {
        int t = tid + 2048;
        ev[4] = ((Dv[0][t] + Dv[1][t + 1]) + (Dv[2][t + 2] + Dv[3][t + 3]))
              + ((Dv[4][t + 4] + Dv[5][t + 5]) + Dv[6][t + 6]);
    } else {
        ev[4] = -INFINITY;
    }

    // ---- per-wave top-8 (shuffle butterfly, in-register removal) ----
    const int wid  = tid >> 6;
    const int lane = tid & 63;
    #pragma unroll 1
    for (int r = 0; r < 8; ++r) {
        float bv = ev[0]; int bk = 0;
        #pragma unroll
        for (int k = 1; k < 5; ++k)
            if (ev[k] > bv) { bv = ev[k]; bk = k; }   // strict >: lower slot wins ties
        int bi = tid + 512 * bk;
        #pragma unroll
        for (int off = 1; off < 64; off <<= 1) {
            float ov = __shfl_xor(bv, off, 64);
            int   oi = __shfl_xor(bi, off, 64);
            if (ov > bv || (ov == bv && oi < bi)) { bv = ov; bi = oi; }
        }
        #pragma unroll
        for (int k = 0; k < 5; ++k)
            if (tid + 512 * k == bi) ev[k] = -INFINITY;
        if (lane == 0) { cand_v[wid * 8 + r] = bv; cand_i[wid * 8 + r] = bi; }
    }
    __syncthreads();

    // ---- wave 0 merges 8x8 candidates -> global top-8 ----
    if (tid < 64) {
        float cv = cand_v[tid];
        int   ci = cand_i[tid];
        #pragma unroll 1
        for (int r = 0; r < 8; ++r) {
            float bv = cv; int bi = ci;
            #pragma unroll
            for (int off = 1; off < 64; off <<= 1) {
                float ov = __shfl_xor(bv, off, 64);
                int   oi = __shfl_xor(bi, off, 64);
                if (ov > bv || (ov == bv && oi < bi)) { bv = ov; bi = oi; }
            }
            if (cv == bv && ci == bi) cv = -INFINITY;   // ci unique -> exact removal
            if (tid == 0) topi[r] = bi;
        }
    }
    __syncthreads();

    // ---- recompute full 6-channel conv1 at the 8 selected positions ----
    if (tid < 96) ((float*)s1p)[tid] = 0.f;      // zero padded stage-2 input
    if (tid < 240) {                             // (r, c, e-decile) partials
        int r = tid / 30, sub = tid - r * 30;
        int c = sub / 5,  eq  = sub - c * 5;
        int t = topi[r];
        float a2 = 0.f;
        #pragma unroll
        for (int kw = 0; kw < 7; ++kw) {
            int g = t + kw - 6;
            if (g >= 0 && g < SEQ) {
                const float* row = emb + (size_t)xb[g] * EMBD + eq * 10;
                const float* wp  = W1 + (kw * 50 + eq * 10) * 6 + c;
                #pragma unroll
                for (int e = 0; e < 10; ++e)
                    a2 = fmaf(row[e], wp[e * 6], a2);
            }
        }
        part[tid] = a2;
    }
    __syncthreads();
    if (tid < 48) {
        int r = tid / 6, c = tid - r * 6;
        float s = b1[c];
        #pragma unroll
        for (int eq = 0; eq < 5; ++eq) s += part[r * 30 + c * 5 + eq];
        s1p[4 + r][c] = 1.0f / (1.0f + expf(-s));    // sigmoid, rows 4..11
    }
    __syncthreads();

    // ---- conv2: [16][6] -> [12][14] ----
    if (tid < 168) {
        int t = tid / 14, c = tid - t * 14;
        float a2 = b2[c];
        #pragma unroll
        for (int kw = 0; kw < 5; ++kw)
            #pragma unroll
            for (int i = 0; i < 6; ++i)
                a2 = fmaf(s1p[t + kw][i], W2[(kw * 6 + i) * 14 + c], a2);
        out2[t][c] = a2;
    }
    __syncthreads();
    if (tid < 12) {
        float s = 0.f;
        #pragma unroll
        for (int c = 0; c < 14; ++c) s += out2[tid][c];
        exc2[tid] = s / 14.0f;
    }
    __syncthreads();

    // ---- top-4 + mean-pool + dense + fused batch-mean finalize ----
    if (tid == 0) {
        float evl[12];
        #pragma unroll
        for (int t = 0; t < 12; ++t) evl[t] = exc2[t];
        int sel[4];
        #pragma unroll 1
        for (int r = 0; r < 4; ++r) {
            float bv = -INFINITY; int bi = 0;
            #pragma unroll
            for (int t = 0; t < 12; ++t)
                if (evl[t] > bv) { bv = evl[t]; bi = t; }  // strict >: lower idx wins
            sel[r] = bi; evl[bi] = -INFINITY;
        }
        float dense = bd[0];
        #pragma unroll
        for (int c = 0; c < 14; ++c) {
            float pool = 0.25f * ((out2[sel[0]][c] + out2[sel[1]][c]) +
                                  (out2[sel[2]][c] + out2[sel[3]][c]));
            dense = fmaf(pool, Wd[c], dense);
        }
        atomicAdd(acc, dense);
        __threadfence();                       // release: acc visible before cnt
        int done = atomicAdd(cnt, 1);
        if (done == 255) {                     // last block finalizes
            __threadfence();                   // acquire
            float s = atomicAdd(acc, 0.0f);    // coherent read of full sum
            out[0] = 1.0f / (1.0f + expf(-s * (1.0f / 256.0f)));
        }
    }
}

extern "C" void kernel_launch(void* const* d_in, const int* in_sizes, int n_in,
                              void* d_out, int out_size, void* d_ws, size_t ws_size,
                              hipStream_t stream) {
    const int*   x   = (const int*)d_in[0];
    const float* emb = (const float*)d_in[1];
    const float* W1  = (const float*)d_in[2];
    const float* b1  = (const float*)d_in[3];
    const float* W2  = (const float*)d_in[4];
    const float* b2  = (const float*)d_in[5];
    const float* Wd  = (const float*)d_in[6];
    const float* bd  = (const float*)d_in[7];
    float* ws = (float*)d_ws;

    // D-path ws layout: [384 .. 384+400000) D, then acc,cnt,acc2,cnt2,dummy
    const size_t needD = (size_t)(384 + VOCAB * 8 + 16) * sizeof(float);

    if (ws_size >= needD) {
        float* D    = ws + 384;
        float* accs = D + VOCAB * 8;           // 5 floats: acc,cnt,acc2,cnt2,dummy
        build_d<<<(VOCAB + 255) / 256, 256, 0, stream>>>(emb, W1, D, accs);
        // real run -> d_out
        dcnn_main<1><<<256, 512, 0, stream>>>(x, emb, W1, b1, W2, b2, Wd, bd,
                                              D, ws, accs, (int*)(accs + 1),
                                              (float*)d_out);
        // PROBE: identical duplicate -> ws dummies (measures T_main via delta)
        dcnn_main<1><<<256, 512, 0, stream>>>(x, emb, W1, b1, W2, b2, Wd, bd,
                                              D, ws, accs + 2, (int*)(accs + 3),
                                              accs + 4);
    } else {
        float* acc = ws + 352;
        int*   cnt = (int*)(ws + 353);
        prep_kernel<<<1, 384, 0, stream>>>(W1, ws);
        dcnn_main<0><<<256, 512, 0, stream>>>(x, emb, W1, b1, W2, b2, Wd, bd,
                                              ws, ws, acc, cnt, (float*)d_out);
    }
}

// Round 9
// 106.662 us; speedup vs baseline: 1.2621x; 1.2621x over previous
//
#include <hip/hip_runtime.h>
#include <math.h>

#define SEQ   2048
#define VOCAB 50000
#define EMBD  50
#define L1OUT 2054      // (2048+12) - 7 + 1
#define NTOK  2060      // padded-token index space i = 0..2059 (g = i-6)
#define DSTR  2064      // LDS row stride for Dv (SoA)

typedef unsigned long long u64;
#define PADKEY 0x007FFFFF80000000ull   // key(v=-inf, idx=0x7FFFFFFF): below all real

// ---- sortable key: larger key <=> (larger v) or (equal v, smaller idx) ----
__device__ inline u64 mkkey(float v, int idx) {
    unsigned u = __float_as_uint(v);
    u = (u & 0x80000000u) ? ~u : (u | 0x80000000u);
    return ((u64)u << 32) | (unsigned)(~idx);
}
__device__ inline void cswap(u64& a, u64& b) {
    if (a < b) { u64 t = a; a = b; b = t; }   // larger -> lower slot (desc)
}
// merge partner's desc-sorted 8-list into mine, keep top-8 (exact, disjoint sets)
__device__ inline void merge8(u64 a[8], const u64 b[8]) {
    u64 m[8];
    #pragma unroll
    for (int i = 0; i < 8; ++i) m[i] = (a[i] > b[7 - i]) ? a[i] : b[7 - i];
    cswap(m[0], m[4]); cswap(m[1], m[5]); cswap(m[2], m[6]); cswap(m[3], m[7]);
    cswap(m[0], m[2]); cswap(m[1], m[3]); cswap(m[4], m[6]); cswap(m[5], m[7]);
    cswap(m[0], m[1]); cswap(m[2], m[3]); cswap(m[4], m[5]); cswap(m[6], m[7]);
    #pragma unroll
    for (int i = 0; i < 8; ++i) a[i] = m[i];
}
// Batcher odd-even mergesort, 8 elements, descending (19 comparators)
__device__ inline void sort8(u64 k[8]) {
    cswap(k[0],k[1]); cswap(k[2],k[3]); cswap(k[4],k[5]); cswap(k[6],k[7]);
    cswap(k[0],k[2]); cswap(k[1],k[3]); cswap(k[4],k[6]); cswap(k[5],k[7]);
    cswap(k[1],k[2]); cswap(k[5],k[6]);
    cswap(k[0],k[4]); cswap(k[1],k[5]); cswap(k[2],k[6]); cswap(k[3],k[7]);
    cswap(k[2],k[4]); cswap(k[3],k[5]);
    cswap(k[1],k[2]); cswap(k[3],k[4]); cswap(k[5],k[6]);
}

// ---- fallback prep (only if ws too small for D) ----------------------------
__global__ void __launch_bounds__(384)
prep_kernel(const float* __restrict__ W1, float* __restrict__ ws) {
    int t = threadIdx.x;
    if (t < 350) {
        float s = 0.f;
        #pragma unroll
        for (int c = 0; c < 6; ++c) s += W1[t * 6 + c];
        ws[t] = s * (1.0f / 6.0f);
    } else if (t < 358) {
        ws[t] = 0.f;
    }
}

// ---- build_d (fused Wm): D[v][0..6] = dot(emb[v], Wm[kw]); zero acc/cnt ---
__global__ void __launch_bounds__(256)
build_d(const float* __restrict__ emb, const float* __restrict__ W1,
        float* __restrict__ D, float* __restrict__ accs) {
    __shared__ float wm[352];
    int t = threadIdx.x;
    for (int i = t; i < 350; i += 256) {
        float s = 0.f;
        #pragma unroll
        for (int c = 0; c < 6; ++c) s += W1[i * 6 + c];
        wm[i] = s * (1.0f / 6.0f);
    }
    if (blockIdx.x == 0 && t < 2) accs[t] = 0.f;   // acc, cnt
    __syncthreads();

    int v = blockIdx.x * 256 + t;
    if (v >= VOCAB) return;
    const float2* row = (const float2*)(emb + (size_t)v * EMBD);
    float d[7] = {0.f, 0.f, 0.f, 0.f, 0.f, 0.f, 0.f};
    for (int e = 0; e < 25; ++e) {
        float2 r = row[e];
        #pragma unroll
        for (int kw = 0; kw < 7; ++kw)
            d[kw] = fmaf(r.y, wm[kw * 50 + 2 * e + 1],
                    fmaf(r.x, wm[kw * 50 + 2 * e], d[kw]));
    }
    float4* out = (float4*)(D + (size_t)v * 8);
    out[0] = make_float4(d[0], d[1], d[2], d[3]);
    out[1] = make_float4(d[4], d[5], d[6], 0.f);
}

// ---- main: one block (512 thr) per batch; fused finalize via atomics ------
template<int USE_D>
__global__ void __launch_bounds__(512, 1)
dcnn_main(const int* __restrict__ x, const float* __restrict__ emb,
          const float* __restrict__ W1, const float* __restrict__ b1,
          const float* __restrict__ W2, const float* __restrict__ b2,
          const float* __restrict__ Wd, const float* __restrict__ bd,
          const float* __restrict__ Dtab, const float* __restrict__ wm,
          float* __restrict__ acc, int* __restrict__ cnt,
          float* __restrict__ out)
{
    __shared__ float Dv[7][DSTR];         // 57.8 KB SoA per-token dot values
    __shared__ u64   cand[8][8];          // per-wave sorted top-8
    __shared__ int   topi[8];
    __shared__ float part[240];
    __shared__ float s1p[16][6];
    __shared__ float out2[12][14];
    __shared__ float exc2[12];

    const int b   = blockIdx.x;
    const int tid = threadIdx.x;
    const int* xb = x + b * SEQ;

    // ---- fully-unrolled 2-phase gather: all xb loads, then all D loads ----
    {
        int tk0 = (tid >= 6) ? xb[tid - 6]   : -1;
        int tk1 = xb[tid + 506];
        int tk2 = xb[tid + 1018];
        int tk3 = xb[tid + 1530];
        int tk4 = (tid < 6)  ? xb[tid + 2042] : -1;

        float4 lo0 = {0,0,0,0}, hi0 = {0,0,0,0};
        float4 lo1 = {0,0,0,0}, hi1 = {0,0,0,0};
        float4 lo2 = {0,0,0,0}, hi2 = {0,0,0,0};
        float4 lo3 = {0,0,0,0}, hi3 = {0,0,0,0};
        float4 lo4 = {0,0,0,0}, hi4 = {0,0,0,0};
        if (USE_D) {
            const float4* dp;
            if (tk0 >= 0) { dp = (const float4*)(Dtab + (size_t)tk0 * 8); lo0 = dp[0]; hi0 = dp[1]; }
            { dp = (const float4*)(Dtab + (size_t)tk1 * 8); lo1 = dp[0]; hi1 = dp[1]; }
            { dp = (const float4*)(Dtab + (size_t)tk2 * 8); lo2 = dp[0]; hi2 = dp[1]; }
            { dp = (const float4*)(Dtab + (size_t)tk3 * 8); lo3 = dp[0]; hi3 = dp[1]; }
            if (tk4 >= 0) { dp = (const float4*)(Dtab + (size_t)tk4 * 8); lo4 = dp[0]; hi4 = dp[1]; }
        } else {
            #pragma unroll
            for (int k = 0; k < 5; ++k) {
                int tk = (k==0)?tk0:(k==1)?tk1:(k==2)?tk2:(k==3)?tk3:tk4;
                if (tk < 0) continue;
                const float2* row = (const float2*)(emb + (size_t)tk * EMBD);
                float dd[7] = {0,0,0,0,0,0,0};
                for (int e = 0; e < 25; ++e) {
                    float2 r = row[e];
                    #pragma unroll
                    for (int kw = 0; kw < 7; ++kw)
                        dd[kw] = fmaf(r.y, wm[kw * 50 + 2 * e + 1],
                                 fmaf(r.x, wm[kw * 50 + 2 * e], dd[kw]));
                }
                float4 l = {dd[0],dd[1],dd[2],dd[3]}, h = {dd[4],dd[5],dd[6],0.f};
                if (k==0){lo0=l;hi0=h;} else if(k==1){lo1=l;hi1=h;}
                else if(k==2){lo2=l;hi2=h;} else if(k==3){lo3=l;hi3=h;}
                else {lo4=l;hi4=h;}
            }
        }
        int i0 = tid, i1 = tid + 512, i2 = tid + 1024, i3 = tid + 1536;
        Dv[0][i0]=lo0.x; Dv[1][i0]=lo0.y; Dv[2][i0]=lo0.z; Dv[3][i0]=lo0.w;
        Dv[4][i0]=hi0.x; Dv[5][i0]=hi0.y; Dv[6][i0]=hi0.z;
        Dv[0][i1]=lo1.x; Dv[1][i1]=lo1.y; Dv[2][i1]=lo1.z; Dv[3][i1]=lo1.w;
        Dv[4][i1]=hi1.x; Dv[5][i1]=hi1.y; Dv[6][i1]=hi1.z;
        Dv[0][i2]=lo2.x; Dv[1][i2]=lo2.y; Dv[2][i2]=lo2.z; Dv[3][i2]=lo2.w;
        Dv[4][i2]=hi2.x; Dv[5][i2]=hi2.y; Dv[6][i2]=hi2.z;
        Dv[0][i3]=lo3.x; Dv[1][i3]=lo3.y; Dv[2][i3]=lo3.z; Dv[3][i3]=lo3.w;
        Dv[4][i3]=hi3.x; Dv[5][i3]=hi3.y; Dv[6][i3]=hi3.z;
        if (tid < 12) {
            int i4 = tid + 2048;
            Dv[0][i4]=lo4.x; Dv[1][i4]=lo4.y; Dv[2][i4]=lo4.z; Dv[3][i4]=lo4.w;
            Dv[4][i4]=hi4.x; Dv[5][i4]=hi4.y; Dv[6][i4]=hi4.z;
        }
    }
    __syncthreads();

    // ---- excitements (registers) + single-pass bitonic top-8 ----
    {
        u64 lst[8];
        #pragma unroll
        for (int k = 0; k < 4; ++k) {
            int t = tid + 512 * k;
            float e = ((Dv[0][t] + Dv[1][t + 1]) + (Dv[2][t + 2] + Dv[3][t + 3]))
                    + ((Dv[4][t + 4] + Dv[5][t + 5]) + Dv[6][t + 6]);
            lst[k] = mkkey(e, t);
        }
        if (tid < 6) {
            int t = tid + 2048;
            float e = ((Dv[0][t] + Dv[1][t + 1]) + (Dv[2][t + 2] + Dv[3][t + 3]))
                    + ((Dv[4][t + 4] + Dv[5][t + 5]) + Dv[6][t + 6]);
            lst[4] = mkkey(e, t);
        } else {
            lst[4] = PADKEY;
        }
        lst[5] = PADKEY; lst[6] = PADKEY; lst[7] = PADKEY;
        sort8(lst);                                   // desc, exact tie order

        #pragma unroll
        for (int off = 1; off < 64; off <<= 1) {      // wave butterfly: 6 steps
            u64 pb[8];
            #pragma unroll
            for (int i = 0; i < 8; ++i) pb[i] = __shfl_xor(lst[i], off, 64);
            merge8(lst, pb);
        }
        const int wid  = tid >> 6;
        const int lane = tid & 63;
        if (lane == 0) {
            #pragma unroll
            for (int i = 0; i < 8; ++i) cand[wid][i] = lst[i];
        }
    }
    __syncthreads();

    // ---- wave 0: merge 8 wave-lists (3 butterfly steps) -> global top-8 ----
    if (tid < 64) {
        u64 lst[8];
        if (tid < 8) {
            #pragma unroll
            for (int i = 0; i < 8; ++i) lst[i] = cand[tid][i];
        } else {
            #pragma unroll
            for (int i = 0; i < 8; ++i) lst[i] = PADKEY;
        }
        #pragma unroll
        for (int off = 1; off < 8; off <<= 1) {
            u64 pb[8];
            #pragma unroll
            for (int i = 0; i < 8; ++i) pb[i] = __shfl_xor(lst[i], off, 64);
            merge8(lst, pb);
        }
        if (tid == 0) {
            #pragma unroll
            for (int r = 0; r < 8; ++r)
                topi[r] = (int)(~(unsigned)(lst[r] & 0xFFFFFFFFull));
        }
    }
    __syncthreads();

    // ---- recompute full 6-channel conv1 at the 8 selected positions ----
    if (tid < 96) ((float*)s1p)[tid] = 0.f;      // zero padded stage-2 input
    if (tid < 240) {                             // (r, c, e-decile) partials
        int r = tid / 30, sub = tid - r * 30;
        int c = sub / 5,  eq  = sub - c * 5;
        int t = topi[r];
        float a2 = 0.f;
        #pragma unroll
        for (int kw = 0; kw < 7; ++kw) {
            int g = t + kw - 6;
            if (g >= 0 && g < SEQ) {
                const float* row = emb + (size_t)xb[g] * EMBD + eq * 10;
                const float* wp  = W1 + (kw * 50 + eq * 10) * 6 + c;
                #pragma unroll
                for (int e = 0; e < 10; ++e)
                    a2 = fmaf(row[e], wp[e * 6], a2);
            }
        }
        part[tid] = a2;
    }
    __syncthreads();
    if (tid < 48) {
        int r = tid / 6, c = tid - r * 6;
        float s = b1[c];
        #pragma unroll
        for (int eq = 0; eq < 5; ++eq) s += part[r * 30 + c * 5 + eq];
        s1p[4 + r][c] = 1.0f / (1.0f + expf(-s));    // sigmoid, rows 4..11
    }
    __syncthreads();

    // ---- conv2: [16][6] -> [12][14] ----
    if (tid < 168) {
        int t = tid / 14, c = tid - t * 14;
        float a2 = b2[c];
        #pragma unroll
        for (int kw = 0; kw < 5; ++kw)
            #pragma unroll
            for (int i = 0; i < 6; ++i)
                a2 = fmaf(s1p[t + kw][i], W2[(kw * 6 + i) * 14 + c], a2);
        out2[t][c] = a2;
    }
    __syncthreads();
    if (tid < 12) {
        float s = 0.f;
        #pragma unroll
        for (int c = 0; c < 14; ++c) s += out2[tid][c];
        exc2[tid] = s / 14.0f;
    }
    __syncthreads();

    // ---- top-4 + mean-pool + dense + fused batch-mean finalize ----
    if (tid == 0) {
        float evl[12];
        #pragma unroll
        for (int t = 0; t < 12; ++t) evl[t] = exc2[t];
        int sel[4];
        #pragma unroll 1
        for (int r = 0; r < 4; ++r) {
            float bv = -INFINITY; int bi = 0;
            #pragma unroll
            for (int t = 0; t < 12; ++t)
                if (evl[t] > bv) { bv = evl[t]; bi = t; }  // strict >: lower idx wins
            sel[r] = bi; evl[bi] = -INFINITY;
        }
        float dense = bd[0];
        #pragma unroll
        for (int c = 0; c < 14; ++c) {
            float pool = 0.25f * ((out2[sel[0]][c] + out2[sel[1]][c]) +
                                  (out2[sel[2]][c] + out2[sel[3]][c]));
            dense = fmaf(pool, Wd[c], dense);
        }
        atomicAdd(acc, dense);
        __threadfence();                       // release: acc visible before cnt
        int done = atomicAdd(cnt, 1);
        if (done == 255) {                     // last block finalizes
            __threadfence();                   // acquire
            float s = atomicAdd(acc, 0.0f);    // coherent read of full sum
            out[0] = 1.0f / (1.0f + expf(-s * (1.0f / 256.0f)));
        }
    }
}

extern "C" void kernel_launch(void* const* d_in, const int* in_sizes, int n_in,
                              void* d_out, int out_size, void* d_ws, size_t ws_size,
                              hipStream_t stream) {
    const int*   x   = (const int*)d_in[0];
    const float* emb = (const float*)d_in[1];
    const float* W1  = (const float*)d_in[2];
    const float* b1  = (const float*)d_in[3];
    const float* W2  = (const float*)d_in[4];
    const float* b2  = (const float*)d_in[5];
    const float* Wd  = (const float*)d_in[6];
    const float* bd  = (const float*)d_in[7];
    float* ws = (float*)d_ws;

    // D-path ws layout: [384 .. 384+400000) D, then acc (f32), cnt (i32)
    const size_t needD = (size_t)(384 + VOCAB * 8 + 8) * sizeof(float);

    if (ws_size >= needD) {
        float* D    = ws + 384;
        float* accs = D + VOCAB * 8;           // acc, cnt
        build_d<<<(VOCAB + 255) / 256, 256, 0, stream>>>(emb, W1, D, accs);
        dcnn_main<1><<<256, 512, 0, stream>>>(x, emb, W1, b1, W2, b2, Wd, bd,
                                              D, ws, accs, (int*)(accs + 1),
                                              (float*)d_out);
    } else {
        float* acc = ws + 352;
        int*   cnt = (int*)(ws + 353);
        prep_kernel<<<1, 384, 0, stream>>>(W1, ws);
        dcnn_main<0><<<256, 512, 0, stream>>>(x, emb, W1, b1, W2, b2, Wd, bd,
                                              ws, ws, acc, cnt, (float*)d_out);
    }
}

// Round 14
// 105.591 us; speedup vs baseline: 1.2749x; 1.0101x over previous
//
#include <hip/hip_runtime.h>
#include <math.h>

#define SEQ   2048
#define VOCAB 50000
#define EMBD  50
#define L1OUT 2054      // (2048+12) - 7 + 1
#define NTOK  2060      // padded-token index space i = 0..2059 (g = i-6)
#define DSTR  2064      // LDS row stride for Dv (SoA)

typedef unsigned long long u64;
#define PADKEY 0x007FFFFF80000000ull   // key(v=-inf, idx=0x7FFFFFFF): below all real

// ---- sortable key: larger key <=> (larger v) or (equal v, smaller idx) ----
__device__ inline u64 mkkey(float v, int idx) {
    unsigned u = __float_as_uint(v);
    u = (u & 0x80000000u) ? ~u : (u | 0x80000000u);
    return ((u64)u << 32) | (unsigned)(~idx);
}
__device__ inline void cswap(u64& a, u64& b) {
    if (a < b) { u64 t = a; a = b; b = t; }   // larger -> lower slot (desc)
}
// merge partner's desc-sorted 8-list into mine, keep top-8 (exact, disjoint sets)
__device__ inline void merge8(u64 a[8], const u64 b[8]) {
    u64 m[8];
    #pragma unroll
    for (int i = 0; i < 8; ++i) m[i] = (a[i] > b[7 - i]) ? a[i] : b[7 - i];
    cswap(m[0], m[4]); cswap(m[1], m[5]); cswap(m[2], m[6]); cswap(m[3], m[7]);
    cswap(m[0], m[2]); cswap(m[1], m[3]); cswap(m[4], m[6]); cswap(m[5], m[7]);
    cswap(m[0], m[1]); cswap(m[2], m[3]); cswap(m[4], m[5]); cswap(m[6], m[7]);
    #pragma unroll
    for (int i = 0; i < 8; ++i) a[i] = m[i];
}
// Batcher odd-even mergesort, 8 elements, descending (19 comparators)
__device__ inline void sort8(u64 k[8]) {
    cswap(k[0],k[1]); cswap(k[2],k[3]); cswap(k[4],k[5]); cswap(k[6],k[7]);
    cswap(k[0],k[2]); cswap(k[1],k[3]); cswap(k[4],k[6]); cswap(k[5],k[7]);
    cswap(k[1],k[2]); cswap(k[5],k[6]);
    cswap(k[0],k[4]); cswap(k[1],k[5]); cswap(k[2],k[6]); cswap(k[3],k[7]);
    cswap(k[2],k[4]); cswap(k[3],k[5]);
    cswap(k[1],k[2]); cswap(k[3],k[4]); cswap(k[5],k[6]);
}

// ---- fallback prep (only if ws too small for D) ----------------------------
__global__ void __launch_bounds__(384)
prep_kernel(const float* __restrict__ W1, float* __restrict__ ws) {
    int t = threadIdx.x;
    if (t < 350) {
        float s = 0.f;
        #pragma unroll
        for (int c = 0; c < 6; ++c) s += W1[t * 6 + c];
        ws[t] = s * (1.0f / 6.0f);
    } else if (t < 358) {
        ws[t] = 0.f;
    }
}

// ---- build_d (fused Wm): D[v][0..6] = dot(emb[v], Wm[kw]); zero acc/cnt ---
__global__ void __launch_bounds__(256)
build_d(const float* __restrict__ emb, const float* __restrict__ W1,
        float* __restrict__ D, float* __restrict__ accs) {
    __shared__ float wm[352];
    int t = threadIdx.x;
    for (int i = t; i < 350; i += 256) {
        float s = 0.f;
        #pragma unroll
        for (int c = 0; c < 6; ++c) s += W1[i * 6 + c];
        wm[i] = s * (1.0f / 6.0f);
    }
    if (blockIdx.x == 0 && t < 2) accs[t] = 0.f;   // acc, cnt
    __syncthreads();

    int v = blockIdx.x * 256 + t;
    if (v >= VOCAB) return;
    const float2* row = (const float2*)(emb + (size_t)v * EMBD);
    float d[7] = {0.f, 0.f, 0.f, 0.f, 0.f, 0.f, 0.f};
    for (int e = 0; e < 25; ++e) {
        float2 r = row[e];
        #pragma unroll
        for (int kw = 0; kw < 7; ++kw)
            d[kw] = fmaf(r.y, wm[kw * 50 + 2 * e + 1],
                    fmaf(r.x, wm[kw * 50 + 2 * e], d[kw]));
    }
    float4* out = (float4*)(D + (size_t)v * 8);
    out[0] = make_float4(d[0], d[1], d[2], d[3]);
    out[1] = make_float4(d[4], d[5], d[6], 0.f);
}

// ---- main: one block (512 thr) per batch; fused finalize via atomics ------
template<int USE_D>
__global__ void __launch_bounds__(512, 1)
dcnn_main(const int* __restrict__ x, const float* __restrict__ emb,
          const float* __restrict__ W1, const float* __restrict__ b1,
          const float* __restrict__ W2, const float* __restrict__ b2,
          const float* __restrict__ Wd, const float* __restrict__ bd,
          const float* __restrict__ Dtab, const float* __restrict__ wm,
          float* __restrict__ acc, int* __restrict__ cnt,
          float* __restrict__ out)
{
    __shared__ float Dv[7][DSTR];         // 57.8 KB SoA per-token dot values
    __shared__ u64   cand[8][8];          // per-wave sorted top-8
    __shared__ int   topi[8];
    __shared__ float s1p[16][6];
    __shared__ float out2[12][14];

    const int b   = blockIdx.x;
    const int tid = threadIdx.x;
    const int* xb = x + b * SEQ;

    // ---- fully-unrolled 2-phase gather: all xb loads, then all D loads ----
    {
        int tk0 = (tid >= 6) ? xb[tid - 6]   : -1;
        int tk1 = xb[tid + 506];
        int tk2 = xb[tid + 1018];
        int tk3 = xb[tid + 1530];
        int tk4 = (tid < 6)  ? xb[tid + 2042] : -1;

        float4 lo0 = {0,0,0,0}, hi0 = {0,0,0,0};
        float4 lo1 = {0,0,0,0}, hi1 = {0,0,0,0};
        float4 lo2 = {0,0,0,0}, hi2 = {0,0,0,0};
        float4 lo3 = {0,0,0,0}, hi3 = {0,0,0,0};
        float4 lo4 = {0,0,0,0}, hi4 = {0,0,0,0};
        if (USE_D) {
            const float4* dp;
            if (tk0 >= 0) { dp = (const float4*)(Dtab + (size_t)tk0 * 8); lo0 = dp[0]; hi0 = dp[1]; }
            { dp = (const float4*)(Dtab + (size_t)tk1 * 8); lo1 = dp[0]; hi1 = dp[1]; }
            { dp = (const float4*)(Dtab + (size_t)tk2 * 8); lo2 = dp[0]; hi2 = dp[1]; }
            { dp = (const float4*)(Dtab + (size_t)tk3 * 8); lo3 = dp[0]; hi3 = dp[1]; }
            if (tk4 >= 0) { dp = (const float4*)(Dtab + (size_t)tk4 * 8); lo4 = dp[0]; hi4 = dp[1]; }
        } else {
            #pragma unroll
            for (int k = 0; k < 5; ++k) {
                int tk = (k==0)?tk0:(k==1)?tk1:(k==2)?tk2:(k==3)?tk3:tk4;
                if (tk < 0) continue;
                const float2* row = (const float2*)(emb + (size_t)tk * EMBD);
                float dd[7] = {0,0,0,0,0,0,0};
                for (int e = 0; e < 25; ++e) {
                    float2 r = row[e];
                    #pragma unroll
                    for (int kw = 0; kw < 7; ++kw)
                        dd[kw] = fmaf(r.y, wm[kw * 50 + 2 * e + 1],
                                 fmaf(r.x, wm[kw * 50 + 2 * e], dd[kw]));
                }
                float4 l = {dd[0],dd[1],dd[2],dd[3]}, h = {dd[4],dd[5],dd[6],0.f};
                if (k==0){lo0=l;hi0=h;} else if(k==1){lo1=l;hi1=h;}
                else if(k==2){lo2=l;hi2=h;} else if(k==3){lo3=l;hi3=h;}
                else {lo4=l;hi4=h;}
            }
        }
        int i0 = tid, i1 = tid + 512, i2 = tid + 1024, i3 = tid + 1536;
        Dv[0][i0]=lo0.x; Dv[1][i0]=lo0.y; Dv[2][i0]=lo0.z; Dv[3][i0]=lo0.w;
        Dv[4][i0]=hi0.x; Dv[5][i0]=hi0.y; Dv[6][i0]=hi0.z;
        Dv[0][i1]=lo1.x; Dv[1][i1]=lo1.y; Dv[2][i1]=lo1.z; Dv[3][i1]=lo1.w;
        Dv[4][i1]=hi1.x; Dv[5][i1]=hi1.y; Dv[6][i1]=hi1.z;
        Dv[0][i2]=lo2.x; Dv[1][i2]=lo2.y; Dv[2][i2]=lo2.z; Dv[3][i2]=lo2.w;
        Dv[4][i2]=hi2.x; Dv[5][i2]=hi2.y; Dv[6][i2]=hi2.z;
        Dv[0][i3]=lo3.x; Dv[1][i3]=lo3.y; Dv[2][i3]=lo3.z; Dv[3][i3]=lo3.w;
        Dv[4][i3]=hi3.x; Dv[5][i3]=hi3.y; Dv[6][i3]=hi3.z;
        if (tid < 12) {
            int i4 = tid + 2048;
            Dv[0][i4]=lo4.x; Dv[1][i4]=lo4.y; Dv[2][i4]=lo4.z; Dv[3][i4]=lo4.w;
            Dv[4][i4]=hi4.x; Dv[5][i4]=hi4.y; Dv[6][i4]=hi4.z;
        }
    }
    __syncthreads();

    // ---- excitements (registers) + single-pass bitonic top-8 ----
    {
        u64 lst[8];
        #pragma unroll
        for (int k = 0; k < 4; ++k) {
            int t = tid + 512 * k;
            float e = ((Dv[0][t] + Dv[1][t + 1]) + (Dv[2][t + 2] + Dv[3][t + 3]))
                    + ((Dv[4][t + 4] + Dv[5][t + 5]) + Dv[6][t + 6]);
            lst[k] = mkkey(e, t);
        }
        if (tid < 6) {
            int t = tid + 2048;
            float e = ((Dv[0][t] + Dv[1][t + 1]) + (Dv[2][t + 2] + Dv[3][t + 3]))
                    + ((Dv[4][t + 4] + Dv[5][t + 5]) + Dv[6][t + 6]);
            lst[4] = mkkey(e, t);
        } else {
            lst[4] = PADKEY;
        }
        lst[5] = PADKEY; lst[6] = PADKEY; lst[7] = PADKEY;
        sort8(lst);                                   // desc, exact tie order

        #pragma unroll
        for (int off = 1; off < 64; off <<= 1) {      // wave butterfly: 6 steps
            u64 pb[8];
            #pragma unroll
            for (int i = 0; i < 8; ++i) pb[i] = __shfl_xor(lst[i], off, 64);
            merge8(lst, pb);
        }
        const int wid  = tid >> 6;
        const int lane = tid & 63;
        if (lane == 0) {
            #pragma unroll
            for (int i = 0; i < 8; ++i) cand[wid][i] = lst[i];
        }
    }
    __syncthreads();

    // ---- wave 0: merge 8 wave-lists -> global top-8; wave 1: zero s1p pads --
    if (tid < 64) {
        u64 lst[8];
        if (tid < 8) {
            #pragma unroll
            for (int i = 0; i < 8; ++i) lst[i] = cand[tid][i];
        } else {
            #pragma unroll
            for (int i = 0; i < 8; ++i) lst[i] = PADKEY;
        }
        #pragma unroll
        for (int off = 1; off < 8; off <<= 1) {
            u64 pb[8];
            #pragma unroll
            for (int i = 0; i < 8; ++i) pb[i] = __shfl_xor(lst[i], off, 64);
            merge8(lst, pb);
        }
        if (tid == 0) {
            #pragma unroll
            for (int r = 0; r < 8; ++r)
                topi[r] = (int)(~(unsigned)(lst[r] & 0xFFFFFFFFull));
        }
    } else if (tid >= 64 && tid < 112) {
        // zero pad rows 0..3 and 12..15 of s1p (rows 4..11 written next phase)
        int i = tid - 64;                 // 0..47
        int r = (i < 24) ? (i / 6) : (12 + (i - 24) / 6);
        int c = (i < 24) ? (i % 6) : ((i - 24) % 6);
        s1p[r][c] = 0.f;
    }
    __syncthreads();

    // ---- fused conv1-recompute + shfl-reduce + sigmoid (384 thr) ----
    if (tid < 384) {
        int grp  = tid >> 3;              // 0..47 = (r, c)
        int eq   = tid & 7;               // 0..4 real, 5..7 idle
        int r    = grp / 6, c = grp - r * 6;
        int t    = topi[r];
        float a2 = 0.f;
        if (eq < 5) {
            #pragma unroll
            for (int kw = 0; kw < 7; ++kw) {
                int g = t + kw - 6;
                if (g >= 0 && g < SEQ) {
                    const float* row = emb + (size_t)xb[g] * EMBD + eq * 10;
                    const float* wp  = W1 + (kw * 50 + eq * 10) * 6 + c;
                    #pragma unroll
                    for (int e = 0; e < 10; ++e)
                        a2 = fmaf(row[e], wp[e * 6], a2);
                }
            }
        }
        // eq0 lane pulls the 4 partials; sum in ORIGINAL serial order.
        // shfls executed by ALL 384 threads (sources active -> defined).
        int base = (tid & 63) & ~7;       // within-wave 8-lane group base
        float p1 = __shfl(a2, base + 1, 64);
        float p2 = __shfl(a2, base + 2, 64);
        float p3 = __shfl(a2, base + 3, 64);
        float p4 = __shfl(a2, base + 4, 64);
        if (eq == 0) {
            float s = b1[c];
            s += a2; s += p1; s += p2; s += p3; s += p4;
            s1p[4 + r][c] = 1.0f / (1.0f + expf(-s));    // sigmoid, rows 4..11
        }
    }
    __syncthreads();

    // ---- conv2: [16][6] -> [12][14] ----
    if (tid < 168) {
        int t = tid / 14, c = tid - t * 14;
        float a2 = b2[c];
        #pragma unroll
        for (int kw = 0; kw < 5; ++kw)
            #pragma unroll
            for (int i = 0; i < 6; ++i)
                a2 = fmaf(s1p[t + kw][i], W2[(kw * 6 + i) * 14 + c], a2);
        out2[t][c] = a2;
    }
    __syncthreads();

    // ---- fused exc2 + top-4 + mean-pool + dense + batch-mean (wave 0) ----
    if (tid < 64) {
        float e2 = 0.f;
        if (tid < 12) {
            float s = 0.f;
            #pragma unroll
            for (int c = 0; c < 14; ++c) s += out2[tid][c];   // original order
            e2 = s / 14.0f;
        }
        // gather executed by ALL 64 lanes of wave 0 (sources active -> defined)
        float evl[12];
        evl[0]  = __shfl(e2, 0, 64);
        evl[1]  = __shfl(e2, 1, 64);
        evl[2]  = __shfl(e2, 2, 64);
        evl[3]  = __shfl(e2, 3, 64);
        evl[4]  = __shfl(e2, 4, 64);
        evl[5]  = __shfl(e2, 5, 64);
        evl[6]  = __shfl(e2, 6, 64);
        evl[7]  = __shfl(e2, 7, 64);
        evl[8]  = __shfl(e2, 8, 64);
        evl[9]  = __shfl(e2, 9, 64);
        evl[10] = __shfl(e2, 10, 64);
        evl[11] = __shfl(e2, 11, 64);
        if (tid == 0) {
            int sel[4];
            #pragma unroll 1
            for (int r = 0; r < 4; ++r) {
                float bv = -INFINITY; int bi = 0;
                #pragma unroll
                for (int t = 0; t < 12; ++t)
                    if (evl[t] > bv) { bv = evl[t]; bi = t; }  // strict >: lower idx wins
                sel[r] = bi; evl[bi] = -INFINITY;
            }
            float dense = bd[0];
            #pragma unroll
            for (int c = 0; c < 14; ++c) {
                float pool = 0.25f * ((out2[sel[0]][c] + out2[sel[1]][c]) +
                                      (out2[sel[2]][c] + out2[sel[3]][c]));
                dense = fmaf(pool, Wd[c], dense);
            }
            atomicAdd(acc, dense);
            __threadfence();                       // release: acc visible before cnt
            int done = atomicAdd(cnt, 1);
            if (done == 255) {                     // last block finalizes
                __threadfence();                   // acquire
                float s = atomicAdd(acc, 0.0f);    // coherent read of full sum
                out[0] = 1.0f / (1.0f + expf(-s * (1.0f / 256.0f)));
            }
        }
    }
}

extern "C" void kernel_launch(void* const* d_in, const int* in_sizes, int n_in,
                              void* d_out, int out_size, void* d_ws, size_t ws_size,
                              hipStream_t stream) {
    const int*   x   = (const int*)d_in[0];
    const float* emb = (const float*)d_in[1];
    const float* W1  = (const float*)d_in[2];
    const float* b1  = (const float*)d_in[3];
    const float* W2  = (const float*)d_in[4];
    const float* b2  = (const float*)d_in[5];
    const float* Wd  = (const float*)d_in[6];
    const float* bd  = (const float*)d_in[7];
    float* ws = (float*)d_ws;

    // D-path ws layout: [384 .. 384+400000) D, then acc (f32), cnt (i32)
    const size_t needD = (size_t)(384 + VOCAB * 8 + 8) * sizeof(float);

    if (ws_size >= needD) {
        float* D    = ws + 384;
        float* accs = D + VOCAB * 8;           // acc, cnt
        build_d<<<(VOCAB + 255) / 256, 256, 0, stream>>>(emb, W1, D, accs);
        dcnn_main<1><<<256, 512, 0, stream>>>(x, emb, W1, b1, W2, b2, Wd, bd,
                                              D, ws, accs, (int*)(accs + 1),
                                              (float*)d_out);
    } else {
        float* acc = ws + 352;
        int*   cnt = (int*)(ws + 353);
        prep_kernel<<<1, 384, 0, stream>>>(W1, ws);
        dcnn_main<0><<<256, 512, 0, stream>>>(x, emb, W1, b1, W2, b2, Wd, bd,
                                              ws, ws, acc, cnt, (float*)d_out);
    }
}